// Round 3
// baseline (690.803 us; speedup 1.0000x reference)
//
#include <hip/hip_runtime.h>
#include <hip/hip_bf16.h>

// Problem: z (8,8192,128) f32, codebook (1024,128) f32.
// Outputs (flat f32, concatenated): z_q [8388608], similarity [67108864],
// ids-as-float [65536], loss_vq [1].

#define BT_TOTAL 65536
#define DDIM 128
#define KCODES 1024
#define ROWS 64           // rows per block
#define KC 64             // codes per chunk
#define NCHUNK (KCODES / KC)
#define TAU 0.125f        // best/second-best gap below which we fp64-refine

// ---------------- pre-pass: transpose codebook + norms ----------------

__global__ __launch_bounds__(256) void vq_pre_transpose(const float* __restrict__ e,
                                                        float* __restrict__ e_t) {
    int g = blockIdx.x * 256 + threadIdx.x;   // 131072 threads
    int d = g >> 10;
    int k = g & 1023;
    e_t[d * KCODES + k] = e[k * DDIM + d];
}

__global__ __launch_bounds__(256) void vq_pre_norms(const float* __restrict__ e,
                                                    float* __restrict__ ne,
                                                    float* __restrict__ ine) {
    int code = blockIdx.x * 4 + (threadIdx.x >> 6);
    int lane = threadIdx.x & 63;
    float v0 = e[code * DDIM + lane];
    float v1 = e[code * DDIM + lane + 64];
    float s = v0 * v0 + v1 * v1;
    #pragma unroll
    for (int m = 1; m < 64; m <<= 1) s += __shfl_xor(s, m);
    if (lane == 0) { ne[code] = s; ine[code] = rsqrtf(s); }
}

// ---------------- main fused kernel ----------------

__global__ __launch_bounds__(256, 2) void vq_main(
    const float* __restrict__ z, const float* __restrict__ cb,
    const float* __restrict__ e_t, const float* __restrict__ ne_g,
    const float* __restrict__ ine_g,
    float* __restrict__ zq_out, float* __restrict__ sim_out,
    float* __restrict__ ids_out, float* __restrict__ loss_out,
    int* __restrict__ fix_cnt, int* __restrict__ fix_rows)
{
    __shared__ float lds_z[DDIM][ROWS];   // 32 KB, d-major
    __shared__ float lds_e[DDIM][KC];     // 32 KB, d-major
    __shared__ float lds_nzp[4][ROWS];    // 1 KB partials
    __shared__ float lds_nz[ROWS];
    __shared__ float lds_inz[ROWS];
    __shared__ int   lds_best[ROWS];
    __shared__ float lds_loss[16];

    const int t = threadIdx.x;
    const int row_base = blockIdx.x * ROWS;

    // ---- stage z tile transposed into LDS (banks = row -> conflict-free) ----
    #pragma unroll
    for (int it = 0; it < 8; ++it) {
        int idx = t + 256 * it;               // 0..2047
        int row = idx & 63;
        int q   = idx >> 6;                   // 0..31 (float4 along d)
        const float4 v = reinterpret_cast<const float4*>(z)[(size_t)(row_base + row) * 32 + q];
        lds_z[4 * q + 0][row] = v.x;
        lds_z[4 * q + 1][row] = v.y;
        lds_z[4 * q + 2][row] = v.z;
        lds_z[4 * q + 3][row] = v.w;
    }
    __syncthreads();

    // ---- per-row ||z||^2 ----
    {
        int row = t & 63, dp = t >> 6;
        float s = 0.f;
        #pragma unroll 8
        for (int d0 = 0; d0 < 32; ++d0) {
            float v = lds_z[dp * 32 + d0][row];
            s = fmaf(v, v, s);
        }
        lds_nzp[dp][row] = s;
    }
    __syncthreads();
    if (t < ROWS) {
        float s = lds_nzp[0][t] + lds_nzp[1][t] + lds_nzp[2][t] + lds_nzp[3][t];
        lds_nz[t]  = s;
        lds_inz[t] = rsqrtf(s);
    }
    __syncthreads();

    const int r = t >> 4;   // 0..15 -> rows 4r..4r+3
    const int c = t & 15;   // 0..15 -> codes 4c..4c+3 within chunk

    float nzr[4], inzr[4];
    #pragma unroll
    for (int i = 0; i < 4; ++i) { nzr[i] = lds_nz[4 * r + i]; inzr[i] = lds_inz[4 * r + i]; }

    float runmin[4], runmin2[4]; int runidx[4];
    #pragma unroll
    for (int i = 0; i < 4; ++i) { runmin[i] = 3.4e38f; runmin2[i] = 3.4e38f; runidx[i] = 0; }

    for (int chunk = 0; chunk < NCHUNK; ++chunk) {
        const int kb = chunk * KC;

        // ---- stage codebook chunk (already d-major in e_t): linear copy ----
        #pragma unroll
        for (int j = 0; j < 8; ++j) {
            int idx = t + 256 * j;            // float4 index within 32KB chunk
            int d  = idx >> 4;                // 0..127
            int cc = idx & 15;                // 0..15 float4 along codes
            float4 v = reinterpret_cast<const float4*>(e_t)[d * (KCODES / 4) + (kb >> 2) + cc];
            *reinterpret_cast<float4*>(&lds_e[d][4 * cc]) = v;
        }
        __syncthreads();

        // ---- 4x4 register microtile over depth ----
        float acc[4][4];
        #pragma unroll
        for (int i = 0; i < 4; ++i)
            #pragma unroll
            for (int j = 0; j < 4; ++j) acc[i][j] = 0.f;

        #pragma unroll 8
        for (int d = 0; d < DDIM; ++d) {
            float4 zv = *reinterpret_cast<const float4*>(&lds_z[d][4 * r]);
            float4 ev = *reinterpret_cast<const float4*>(&lds_e[d][4 * c]);
            float za[4] = { zv.x, zv.y, zv.z, zv.w };
            float ea[4] = { ev.x, ev.y, ev.z, ev.w };
            #pragma unroll
            for (int i = 0; i < 4; ++i)
                #pragma unroll
                for (int j = 0; j < 4; ++j)
                    acc[i][j] = fmaf(za[i], ea[j], acc[i][j]);
        }

        // ---- epilogue: similarity + running argmin (best + second-best) ----
        const float4 nev  = reinterpret_cast<const float4*>(ne_g)[chunk * 16 + c];
        const float4 inev = reinterpret_cast<const float4*>(ine_g)[chunk * 16 + c];
        float nea[4]  = { nev.x, nev.y, nev.z, nev.w };
        float inea[4] = { inev.x, inev.y, inev.z, inev.w };

        #pragma unroll
        for (int i = 0; i < 4; ++i) {
            float sa[4];
            #pragma unroll
            for (int j = 0; j < 4; ++j) {
                float dot = acc[i][j];
                sa[j] = dot * inzr[i] * inea[j];
                // numpy rounding order: ((-2*dot) + nz) + ne ; strict < keeps first occurrence
                float dd = ((-2.0f * dot) + nzr[i]) + nea[j];
                int kidx = kb + 4 * c + j;
                if (dd < runmin[i]) { runmin2[i] = runmin[i]; runmin[i] = dd; runidx[i] = kidx; }
                else if (dd < runmin2[i]) runmin2[i] = dd;
            }
            float4 sv; sv.x = sa[0]; sv.y = sa[1]; sv.z = sa[2]; sv.w = sa[3];
            reinterpret_cast<float4*>(sim_out)[(size_t)(row_base + 4 * r + i) * (KCODES / 4) + (kb >> 2) + c] = sv;
        }
        __syncthreads();   // before next chunk overwrites lds_e
    }

    // ---- cross-lane argmin reduce over the 16 c-lanes (keeps best2) ----
    #pragma unroll
    for (int m = 1; m < 16; m <<= 1) {
        #pragma unroll
        for (int i = 0; i < 4; ++i) {
            float om1 = __shfl_xor(runmin[i], m);
            float om2 = __shfl_xor(runmin2[i], m);
            int   oi  = __shfl_xor(runidx[i], m);
            float nm2 = fminf(fminf(runmin2[i], om2), fmaxf(runmin[i], om1));
            if (om1 < runmin[i] || (om1 == runmin[i] && oi < runidx[i])) {
                runmin[i] = om1; runidx[i] = oi;
            }
            runmin2[i] = nm2;
        }
    }
    if (c == 0) {
        float psum = 0.f;
        #pragma unroll
        for (int i = 0; i < 4; ++i) {
            int row = 4 * r + i;
            lds_best[row] = runidx[i];
            ids_out[row_base + row] = (float)runidx[i];
            psum += sqrtf(fmaxf(runmin[i], 0.f));
            if (runmin2[i] - runmin[i] < TAU) {
                int slot = atomicAdd(fix_cnt, 1);
                fix_rows[slot] = row_base + row;
            }
        }
        lds_loss[r] = psum;
    }
    __syncthreads();

    if (t == 0) {
        float s = 0.f;
        #pragma unroll
        for (int i = 0; i < 16; ++i) s += lds_loss[i];
        // loss_vq = (1 + BETA) * mean(||z - z_q||)
        atomicAdd(loss_out, s * (1.25f / 65536.0f));
    }

    // ---- z_q gather ----
    #pragma unroll
    for (int j2 = 0; j2 < 8; ++j2) {
        int idx = t + 256 * j2;               // 0..2047
        int row = idx >> 5;                   // 0..63
        int q   = idx & 31;                   // float4 along d
        int b   = lds_best[row];
        float4 v = reinterpret_cast<const float4*>(cb)[b * 32 + q];
        reinterpret_cast<float4*>(zq_out)[(size_t)(row_base + row) * 32 + q] = v;
    }
}

// ---------------- fp64 refinement for near-tie rows ----------------

__global__ __launch_bounds__(256) void vq_fixup(
    const float* __restrict__ z, const float* __restrict__ cb,
    const float* __restrict__ e_t,
    const int* __restrict__ fix_cnt, const int* __restrict__ fix_rows,
    float* __restrict__ zq_out, float* __restrict__ ids_out)
{
    __shared__ float zl[DDIM];
    __shared__ double wbest[4];
    __shared__ int    wbidx[4];
    const int n = *fix_cnt;
    const int tid = threadIdx.x;

    for (int item = blockIdx.x; item < n; item += gridDim.x) {
        const int row = fix_rows[item];
        if (tid < DDIM) zl[tid] = z[(size_t)row * DDIM + tid];
        __syncthreads();

        double bd = 1.0e300; int bi = 0;
        #pragma unroll
        for (int c4 = 0; c4 < 4; ++c4) {
            const int code = c4 * 256 + tid;
            double acc = 0.0;
            #pragma unroll 4
            for (int d = 0; d < DDIM; ++d) {
                double diff = (double)zl[d] - (double)e_t[d * KCODES + code];
                acc = fma(diff, diff, acc);
            }
            if (acc < bd) { bd = acc; bi = code; }
        }
        const int lane = tid & 63, w = tid >> 6;
        #pragma unroll
        for (int m = 1; m < 64; m <<= 1) {
            double od = __shfl_xor(bd, m);
            int    oi = __shfl_xor(bi, m);
            if (od < bd || (od == bd && oi < bi)) { bd = od; bi = oi; }
        }
        if (lane == 0) { wbest[w] = bd; wbidx[w] = bi; }
        __syncthreads();
        if (tid == 0) {
            double b0 = wbest[0]; int i0 = wbidx[0];
            #pragma unroll
            for (int i = 1; i < 4; ++i)
                if (wbest[i] < b0 || (wbest[i] == b0 && wbidx[i] < i0)) { b0 = wbest[i]; i0 = wbidx[i]; }
            wbidx[0] = i0;
            ids_out[row] = (float)i0;
        }
        __syncthreads();
        const int b = wbidx[0];
        if (tid < 32) {
            float4 v = reinterpret_cast<const float4*>(cb)[b * 32 + tid];
            reinterpret_cast<float4*>(zq_out)[(size_t)row * 32 + tid] = v;
        }
        __syncthreads();
    }
}

// ---------------- launcher ----------------

extern "C" void kernel_launch(void* const* d_in, const int* in_sizes, int n_in,
                              void* d_out, int out_size, void* d_ws, size_t ws_size,
                              hipStream_t stream) {
    const float* z  = (const float*)d_in[0];
    const float* cb = (const float*)d_in[1];

    float* out  = (float*)d_out;
    float* zq   = out;                       // 8388608
    float* sim  = out + 8388608;             // 67108864
    float* ids  = out + 75497472;            // 65536
    float* loss = out + 75563008;            // 1

    float* e_t      = (float*)d_ws;          // 128*1024 floats = 512 KB
    float* ne       = e_t + 131072;          // 1024 floats
    float* ine      = ne + 1024;             // 1024 floats
    int*   fix_cnt  = (int*)(ine + 1024);    // 1 int
    int*   fix_rows = fix_cnt + 1;           // 65536 ints

    hipMemsetAsync(loss, 0, sizeof(float), stream);
    hipMemsetAsync(fix_cnt, 0, sizeof(int), stream);

    vq_pre_transpose<<<512, 256, 0, stream>>>(cb, e_t);
    vq_pre_norms<<<256, 256, 0, stream>>>(cb, ne, ine);
    vq_main<<<BT_TOTAL / ROWS, 256, 0, stream>>>(z, cb, e_t, ne, ine,
                                                 zq, sim, ids, loss, fix_cnt, fix_rows);
    vq_fixup<<<256, 256, 0, stream>>>(z, cb, e_t, fix_cnt, fix_rows, zq, ids);
}

// Round 4
// 634.747 us; speedup vs baseline: 1.0883x; 1.0883x over previous
//
#include <hip/hip_runtime.h>
#include <hip/hip_bf16.h>

// Problem: z (8,8192,128) f32, codebook (1024,128) f32.
// Outputs (flat f32, concatenated): z_q [8388608], similarity [67108864],
// ids-as-float [65536], loss_vq [1].
//
// Strategy: dot = zh*eh + zh*el + zl*eh via bf16 MFMA (error ~6e-4 abs),
// argmin protected by best2-gap flag (TAU) + fp64 full-scan fixup.

#define BT_TOTAL 65536
#define DDIM 128
#define KCODES 1024
#define TAU 0.125f

typedef __attribute__((ext_vector_type(8))) short bf16x8;
typedef __attribute__((ext_vector_type(4))) float f32x4;

__device__ __forceinline__ unsigned short f32_to_bf16_rne(float x) {
    unsigned int u = __float_as_uint(x);
    unsigned int r = u + 0x7FFFu + ((u >> 16) & 1u);
    return (unsigned short)(r >> 16);
}
__device__ __forceinline__ float bf16u_to_f32(unsigned short s) {
    return __uint_as_float(((unsigned int)s) << 16);
}

// ---------------- pre-passes ----------------

// split codebook into hi/lo bf16 planes (row-major [code][d])
__global__ __launch_bounds__(256) void vq_pre_cb(const float* __restrict__ cb,
                                                 unsigned short* __restrict__ cb_hi,
                                                 unsigned short* __restrict__ cb_lo) {
    int gidx = blockIdx.x * 256 + threadIdx.x;          // 32768 float4's
    float4 v = reinterpret_cast<const float4*>(cb)[gidx];
    float a[4] = { v.x, v.y, v.z, v.w };
    ushort4 h, l;
    unsigned short hs[4], ls[4];
    #pragma unroll
    for (int j = 0; j < 4; ++j) {
        hs[j] = f32_to_bf16_rne(a[j]);
        ls[j] = f32_to_bf16_rne(a[j] - bf16u_to_f32(hs[j]));
    }
    h.x = hs[0]; h.y = hs[1]; h.z = hs[2]; h.w = hs[3];
    l.x = ls[0]; l.y = ls[1]; l.z = ls[2]; l.w = ls[3];
    reinterpret_cast<ushort4*>(cb_hi)[gidx] = h;
    reinterpret_cast<ushort4*>(cb_lo)[gidx] = l;
}

__global__ __launch_bounds__(256) void vq_pre_norms(const float* __restrict__ e,
                                                    float* __restrict__ ne,
                                                    float* __restrict__ ine) {
    int code = blockIdx.x * 4 + (threadIdx.x >> 6);
    int lane = threadIdx.x & 63;
    float v0 = e[code * DDIM + lane];
    float v1 = e[code * DDIM + lane + 64];
    float s = v0 * v0 + v1 * v1;
    #pragma unroll
    for (int m = 1; m < 64; m <<= 1) s += __shfl_xor(s, m);
    if (lane == 0) { ne[code] = s; ine[code] = rsqrtf(s); }
}

// d-major codebook copy for the fp64 fixup
__global__ __launch_bounds__(256) void vq_pre_transpose(const float* __restrict__ e,
                                                        float* __restrict__ e_t) {
    int g = blockIdx.x * 256 + threadIdx.x;   // 131072 threads
    int d = g >> 10;
    int k = g & 1023;
    e_t[d * KCODES + k] = e[k * DDIM + d];
}

// per-row ||z||^2
__global__ __launch_bounds__(256) void vq_pre_znorm(const float* __restrict__ z,
                                                    float* __restrict__ nz) {
    int wg = blockIdx.x * 4 + (threadIdx.x >> 6);   // 8192 waves
    int lane = threadIdx.x & 63;
    #pragma unroll
    for (int it = 0; it < 8; ++it) {
        int row = wg + 8192 * it;
        float2 v = reinterpret_cast<const float2*>(z)[(size_t)row * 64 + lane];
        float s = v.x * v.x + v.y * v.y;
        #pragma unroll
        for (int m = 1; m < 64; m <<= 1) s += __shfl_xor(s, m);
        if (lane == 0) nz[row] = s;
    }
}

// ---------------- main MFMA kernel ----------------
// 512 blocks x 256 thr; wave = 32 rows x all 1024 codes (32 chunks of 32).
// A (z rows) resident in regs as hi/lo bf16 fragments; B streamed from L2.

__global__ __launch_bounds__(256, 2) void vq_main(
    const float* __restrict__ z, const float* __restrict__ cb,
    const unsigned short* __restrict__ cb_hi, const unsigned short* __restrict__ cb_lo,
    const float* __restrict__ ne_g, const float* __restrict__ ine_g,
    const float* __restrict__ nz_g,
    float* __restrict__ zq_out, float* __restrict__ sim_out,
    float* __restrict__ ids_out, float* __restrict__ loss_out,
    int* __restrict__ fix_cnt, int* __restrict__ fix_rows)
{
    __shared__ int s_best[4][32];

    const int t = threadIdx.x;
    const int wave = t >> 6, lane = t & 63;
    const int g = lane >> 4, li = lane & 15;
    const int rbase = (blockIdx.x * 4 + wave) * 32;

    // ---- A fragments: lane holds z[rbase+rt*16+li][ks*32+g*8 .. +8) as hi/lo bf16 ----
    bf16x8 Ah[2][4], Al[2][4];
    #pragma unroll
    for (int rt = 0; rt < 2; ++rt) {
        const int row = rbase + rt * 16 + li;
        const float4* pz = reinterpret_cast<const float4*>(z + (size_t)row * DDIM);
        #pragma unroll
        for (int ks = 0; ks < 4; ++ks) {
            float4 v0 = pz[ks * 8 + g * 2];
            float4 v1 = pz[ks * 8 + g * 2 + 1];
            float a[8] = { v0.x, v0.y, v0.z, v0.w, v1.x, v1.y, v1.z, v1.w };
            bf16x8 h, lo;
            #pragma unroll
            for (int j = 0; j < 8; ++j) {
                unsigned short hs = f32_to_bf16_rne(a[j]);
                float fh = bf16u_to_f32(hs);
                unsigned short ls = f32_to_bf16_rne(a[j] - fh);
                h[j] = (short)hs; lo[j] = (short)ls;
            }
            Ah[rt][ks] = h; Al[rt][ks] = lo;
        }
    }

    // ---- per-lane row norms; lane's rows are rbase + rt*16 + g*4 + q ----
    float nzr[2][4], inzr[2][4];
    #pragma unroll
    for (int rt = 0; rt < 2; ++rt)
        #pragma unroll
        for (int q = 0; q < 4; ++q) {
            float n = nz_g[rbase + rt * 16 + g * 4 + q];
            nzr[rt][q] = n; inzr[rt][q] = rsqrtf(n);
        }

    float runmin[2][4], runmin2[2][4]; int runidx[2][4];
    #pragma unroll
    for (int rt = 0; rt < 2; ++rt)
        #pragma unroll
        for (int q = 0; q < 4; ++q) { runmin[rt][q] = 3.4e38f; runmin2[rt][q] = 3.4e38f; runidx[rt][q] = 0; }

    for (int chunk = 0; chunk < 32; ++chunk) {
        const int cbase = chunk * 32;
        f32x4 acc[2][2];
        #pragma unroll
        for (int rt = 0; rt < 2; ++rt)
            #pragma unroll
            for (int ct = 0; ct < 2; ++ct) acc[rt][ct] = (f32x4){0.f, 0.f, 0.f, 0.f};

        #pragma unroll
        for (int ct = 0; ct < 2; ++ct) {
            const int code = cbase + ct * 16 + li;
            const bf16x8* ph = reinterpret_cast<const bf16x8*>(cb_hi + (size_t)code * DDIM);
            const bf16x8* pl = reinterpret_cast<const bf16x8*>(cb_lo + (size_t)code * DDIM);
            bf16x8 Bh[4], Bl[4];
            #pragma unroll
            for (int ks = 0; ks < 4; ++ks) { Bh[ks] = ph[ks * 4 + g]; Bl[ks] = pl[ks * 4 + g]; }
            #pragma unroll
            for (int ks = 0; ks < 4; ++ks) {
                #pragma unroll
                for (int rt = 0; rt < 2; ++rt) {
                    acc[rt][ct] = __builtin_amdgcn_mfma_f32_16x16x32_bf16(Ah[rt][ks], Bh[ks], acc[rt][ct], 0, 0, 0);
                    acc[rt][ct] = __builtin_amdgcn_mfma_f32_16x16x32_bf16(Ah[rt][ks], Bl[ks], acc[rt][ct], 0, 0, 0);
                    acc[rt][ct] = __builtin_amdgcn_mfma_f32_16x16x32_bf16(Al[rt][ks], Bh[ks], acc[rt][ct], 0, 0, 0);
                }
            }
        }

        // ---- epilogue: sim store + best2 update ----
        // D layout: col = li, row = g*4 + q (within 16x16 tile)  [m89-verified]
        #pragma unroll
        for (int ct = 0; ct < 2; ++ct) {
            const int code = cbase + ct * 16 + li;
            const float ne_c = ne_g[code], ine_c = ine_g[code];
            #pragma unroll
            for (int rt = 0; rt < 2; ++rt) {
                #pragma unroll
                for (int q = 0; q < 4; ++q) {
                    float dot = acc[rt][ct][q];
                    int row = rbase + rt * 16 + g * 4 + q;
                    sim_out[(size_t)row * KCODES + code] = dot * inzr[rt][q] * ine_c;
                    float dd = ((-2.0f * dot) + nzr[rt][q]) + ne_c;   // numpy rounding order
                    if (dd < runmin[rt][q]) {
                        runmin2[rt][q] = runmin[rt][q]; runmin[rt][q] = dd; runidx[rt][q] = code;
                    } else if (dd < runmin2[rt][q]) runmin2[rt][q] = dd;
                }
            }
        }
    }

    // ---- cross-lane argmin reduce over the 16 li-lanes (keeps best2) ----
    #pragma unroll
    for (int m = 1; m < 16; m <<= 1) {
        #pragma unroll
        for (int rt = 0; rt < 2; ++rt)
            #pragma unroll
            for (int q = 0; q < 4; ++q) {
                float om1 = __shfl_xor(runmin[rt][q], m);
                float om2 = __shfl_xor(runmin2[rt][q], m);
                int   oi  = __shfl_xor(runidx[rt][q], m);
                float nm2 = fminf(fminf(runmin2[rt][q], om2), fmaxf(runmin[rt][q], om1));
                if (om1 < runmin[rt][q] || (om1 == runmin[rt][q] && oi < runidx[rt][q])) {
                    runmin[rt][q] = om1; runidx[rt][q] = oi;
                }
                runmin2[rt][q] = nm2;
            }
    }

    float loss_p = 0.f;
    if (li == 0) {
        #pragma unroll
        for (int rt = 0; rt < 2; ++rt)
            #pragma unroll
            for (int q = 0; q < 4; ++q) {
                int rl = rt * 16 + g * 4 + q;
                int idx = runidx[rt][q];
                s_best[wave][rl] = idx;
                ids_out[rbase + rl] = (float)idx;
                loss_p += sqrtf(fmaxf(runmin[rt][q], 0.f));
                if (runmin2[rt][q] - runmin[rt][q] < TAU) {
                    int slot = atomicAdd(fix_cnt, 1);
                    fix_rows[slot] = rbase + rl;
                }
            }
    }
    loss_p += __shfl_xor(loss_p, 16);
    loss_p += __shfl_xor(loss_p, 32);
    if (lane == 0) atomicAdd(loss_out, loss_p * (1.25f / 65536.0f));

    __syncthreads();

    // ---- z_q gather: wave writes its 32 rows ----
    #pragma unroll
    for (int it = 0; it < 16; ++it) {
        int idx2 = it * 64 + lane;            // 0..1023
        int rl = idx2 >> 5;                   // 0..31
        int qq = idx2 & 31;                   // float4 along d
        int b = s_best[wave][rl];
        float4 v = reinterpret_cast<const float4*>(cb)[b * 32 + qq];
        reinterpret_cast<float4*>(zq_out)[(size_t)(rbase + rl) * 32 + qq] = v;
    }
}

// ---------------- fp64 refinement for near-tie rows ----------------

__global__ __launch_bounds__(256) void vq_fixup(
    const float* __restrict__ z, const float* __restrict__ cb,
    const float* __restrict__ e_t,
    const int* __restrict__ fix_cnt, const int* __restrict__ fix_rows,
    float* __restrict__ zq_out, float* __restrict__ ids_out)
{
    __shared__ float zl[DDIM];
    __shared__ double wbest[4];
    __shared__ int    wbidx[4];
    const int n = *fix_cnt;
    const int tid = threadIdx.x;

    for (int item = blockIdx.x; item < n; item += gridDim.x) {
        const int row = fix_rows[item];
        if (tid < DDIM) zl[tid] = z[(size_t)row * DDIM + tid];
        __syncthreads();

        double bd = 1.0e300; int bi = 0;
        #pragma unroll
        for (int c4 = 0; c4 < 4; ++c4) {
            const int code = c4 * 256 + tid;
            double acc = 0.0;
            #pragma unroll 4
            for (int d = 0; d < DDIM; ++d) {
                double diff = (double)zl[d] - (double)e_t[d * KCODES + code];
                acc = fma(diff, diff, acc);
            }
            if (acc < bd) { bd = acc; bi = code; }
        }
        const int lane = tid & 63, w = tid >> 6;
        #pragma unroll
        for (int m = 1; m < 64; m <<= 1) {
            double od = __shfl_xor(bd, m);
            int    oi = __shfl_xor(bi, m);
            if (od < bd || (od == bd && oi < bi)) { bd = od; bi = oi; }
        }
        if (lane == 0) { wbest[w] = bd; wbidx[w] = bi; }
        __syncthreads();
        if (tid == 0) {
            double b0 = wbest[0]; int i0 = wbidx[0];
            #pragma unroll
            for (int i = 1; i < 4; ++i)
                if (wbest[i] < b0 || (wbest[i] == b0 && wbidx[i] < i0)) { b0 = wbest[i]; i0 = wbidx[i]; }
            wbidx[0] = i0;
            ids_out[row] = (float)i0;
        }
        __syncthreads();
        const int b = wbidx[0];
        if (tid < 32) {
            float4 v = reinterpret_cast<const float4*>(cb)[b * 32 + tid];
            reinterpret_cast<float4*>(zq_out)[(size_t)row * 32 + tid] = v;
        }
        __syncthreads();
    }
}

// ---------------- launcher ----------------

extern "C" void kernel_launch(void* const* d_in, const int* in_sizes, int n_in,
                              void* d_out, int out_size, void* d_ws, size_t ws_size,
                              hipStream_t stream) {
    const float* z  = (const float*)d_in[0];
    const float* cb = (const float*)d_in[1];

    float* out  = (float*)d_out;
    float* zq   = out;                       // 8388608
    float* sim  = out + 8388608;             // 67108864
    float* ids  = out + 75497472;            // 65536
    float* loss = out + 75563008;            // 1

    float* e_t = (float*)d_ws;               // 131072 f
    float* ne  = e_t + 131072;               // 1024 f
    float* ine = ne + 1024;                  // 1024 f
    float* nz  = ine + 1024;                 // 65536 f
    unsigned short* cb_hi = (unsigned short*)(nz + 65536);   // 131072 ushort
    unsigned short* cb_lo = cb_hi + 131072;                  // 131072 ushort
    int* fix_cnt  = (int*)(cb_lo + 131072);
    int* fix_rows = fix_cnt + 1;             // up to 65536 ints

    hipMemsetAsync(loss, 0, sizeof(float), stream);
    hipMemsetAsync(fix_cnt, 0, sizeof(int), stream);

    vq_pre_cb<<<128, 256, 0, stream>>>(cb, cb_hi, cb_lo);
    vq_pre_norms<<<256, 256, 0, stream>>>(cb, ne, ine);
    vq_pre_transpose<<<512, 256, 0, stream>>>(cb, e_t);
    vq_pre_znorm<<<2048, 256, 0, stream>>>(z, nz);

    vq_main<<<512, 256, 0, stream>>>(z, cb, cb_hi, cb_lo, ne, ine, nz,
                                     zq, sim, ids, loss, fix_cnt, fix_rows);
    vq_fixup<<<256, 256, 0, stream>>>(z, cb, e_t, fix_cnt, fix_rows, zq, ids);
}